// Round 6
// baseline (260.453 us; speedup 1.0000x reference)
//
#include <hip/hip_runtime.h>
#include <hip/hip_fp16.h>

#define GRAVITY_F 9.81f
#define TAB_CAP_V 520000

typedef int   v4i __attribute__((ext_vector_type(4)));
typedef float v4f __attribute__((ext_vector_type(4), aligned(16)));

// Static module-scope gather table: fp16 (x,y,z,pad) at 8 B/vertex.
// V=500K -> 4.00 MB: fits the 4.19 MB per-XCD L2. Rounds 2-4 proved the
// 6 MB fp32 pos_next table cannot be gathered at high MLP without
// +115-145 MB of L2-miss fill traffic; a <=4 MB table can stay resident.
// Static __device__ storage because ws_size < 3 MB (round-0 and round-5
// workspace gates both failed -> fallback ran, absmax stayed 0.0).
__device__ __align__(16) uint2 g_tab[TAB_CAP_V + 2];

__device__ __forceinline__ float blockReduceSum(float val) {
    #pragma unroll
    for (int off = 32; off > 0; off >>= 1)
        val += __shfl_down(val, off, 64);
    __shared__ float smem[16];
    const int lane = threadIdx.x & 63;
    const int wave = threadIdx.x >> 6;
    if (lane == 0) smem[wave] = val;
    __syncthreads();
    const int nwaves = (blockDim.x + 63) >> 6;
    val = 0.0f;
    if (wave == 0) {
        if (lane < nwaves) val = smem[lane];
        #pragma unroll
        for (int off = 8; off > 0; off >>= 1)
            val += __shfl_down(val, off, 64);
    }
    return val;  // valid on thread 0 only
}

__device__ __forceinline__ uint2 packVert(float x, float y, float z) {
    uint2 w;
    w.x = (unsigned)__half_as_ushort(__float2half(x))
        | ((unsigned)__half_as_ushort(__float2half(y)) << 16);
    w.y = (unsigned)__half_as_ushort(__float2half(z));
    return w;
}

__device__ __forceinline__ void dec3(uint2 w, float* o) {
    o[0] = __half2float(__ushort_as_half((unsigned short)(w.x & 0xffffu)));
    o[1] = __half2float(__ushort_as_half((unsigned short)(w.x >> 16)));
    o[2] = __half2float(__ushort_as_half((unsigned short)(w.y & 0xffffu)));
}

// Kernel 1: pack pos_next -> fp16 table AND compute vertex terms (it
// already loads pn; fusing saves a second pass). 4 verts/thread, all
// vector loads 16B-aligned; pc/pp/mass nontemporal (single-use).
__global__ void __launch_bounds__(256)
pack_vert_kernel(const float* __restrict__ pn,
                 const float* __restrict__ pc,
                 const float* __restrict__ pp,
                 const float* __restrict__ mass,
                 float* __restrict__ partials,
                 int V, int doPack, float sI, float sG) {
    const int g  = blockIdx.x * blockDim.x + threadIdx.x;
    const int v0 = g * 4;
    float local = 0.0f;

    if (v0 + 4 <= V) {
        const v4f m4 = *(const v4f*)(mass + v0);
        const v4f n0 = *(const v4f*)(pn + 3 * v0);
        const v4f n1 = *(const v4f*)(pn + 3 * v0 + 4);
        const v4f n2 = *(const v4f*)(pn + 3 * v0 + 8);
        const v4f c0 = __builtin_nontemporal_load((const v4f*)(pc + 3 * v0));
        const v4f c1 = __builtin_nontemporal_load((const v4f*)(pc + 3 * v0 + 4));
        const v4f c2 = __builtin_nontemporal_load((const v4f*)(pc + 3 * v0 + 8));
        const v4f q0 = __builtin_nontemporal_load((const v4f*)(pp + 3 * v0));
        const v4f q1 = __builtin_nontemporal_load((const v4f*)(pp + 3 * v0 + 4));
        const v4f q2 = __builtin_nontemporal_load((const v4f*)(pp + 3 * v0 + 8));
        const v4f N[3] = { n0, n1, n2 };
        const v4f C[3] = { c0, c1, c2 };
        const v4f Q[3] = { q0, q1, q2 };

        if (doPack) {
            uint2 w[4];
            #pragma unroll
            for (int i = 0; i < 4; ++i) {
                const int k = 3 * i;
                w[i] = packVert(N[(k + 0) >> 2][(k + 0) & 3],
                                N[(k + 1) >> 2][(k + 1) & 3],
                                N[(k + 2) >> 2][(k + 2) & 3]);
            }
            uint4* dst = reinterpret_cast<uint4*>(&g_tab[v0]);  // 32g bytes: 16B-aligned
            dst[0] = make_uint4(w[0].x, w[0].y, w[1].x, w[1].y);
            dst[1] = make_uint4(w[2].x, w[2].y, w[3].x, w[3].y);
        }

        #pragma unroll
        for (int i = 0; i < 4; ++i) {
            float acc = 0.0f;
            #pragma unroll
            for (int r = 0; r < 3; ++r) {
                const int k = 3 * i + r;
                const float a = N[k >> 2][k & 3] + Q[k >> 2][k & 3]
                              - 2.0f * C[k >> 2][k & 3];
                acc += a * a;
            }
            const int ky = 3 * i + 1;
            const float y = C[ky >> 2][ky & 3];
            local += sI * (m4[i] * acc) + sG * (m4[i] * y);
        }
    } else {
        for (int v = v0; v < V; ++v) {
            const float m  = mass[v];
            const float x0 = pn[3 * v + 0];
            const float x1 = pn[3 * v + 1];
            const float x2 = pn[3 * v + 2];
            if (doPack) g_tab[v] = packVert(x0, x1, x2);
            const float p0 = pc[3 * v + 0];
            const float y  = pc[3 * v + 1];
            const float p2 = pc[3 * v + 2];
            const float a0 = x0 + pp[3 * v + 0] - 2.0f * p0;
            const float a1 = x1 + pp[3 * v + 1] - 2.0f * y;
            const float a2 = x2 + pp[3 * v + 2] - 2.0f * p2;
            local += sI * (m * (a0 * a0 + a1 * a1 + a2 * a2)) + sG * (m * y);
        }
    }

    const float tot = blockReduceSum(local);
    if (threadIdx.x == 0) partials[blockIdx.x] = tot;
}

// Kernel 2: element terms. 4 CONSECUTIVE elems/thread so rinv/vols/idx are
// fully-coalesced aligned dwordx4 (each 64B line touched exactly once:
// 2.25 trans/elem vs 5.06 scalar). PACKED: gathers are ONE aligned dwordx2
// from the L2-resident table (8M trans vs 24M scalar fp32). The asm pin
// keeps the whole cluster in flight (round-2-proven: 1.7 -> 3 TB/s).
// Precision guard: if |det| < 0.5 (~1% of elems), re-gather that element
// in fp32 from pn and recompute exactly -- removes the log-det clamp-flip
// error tail that fp16 positions would otherwise cause.
template <bool PACKED>
__global__ void __launch_bounds__(256, 4)
elem_kernel(const float* __restrict__ pn,
            const int*   __restrict__ elems,
            const float* __restrict__ vols,
            const float* __restrict__ rinv,
            const float* __restrict__ lam_p,
            const float* __restrict__ mu_p,
            float* __restrict__ partials,
            int E, float sS) {
    const float lam = lam_p[0];
    const float mu  = mu_p[0];
    float local = 0.0f;

    const int t  = blockIdx.x * 256 + threadIdx.x;  // element-quad index
    const int e0 = 4 * t;

    float rf[36];
    v4i   idx[4];
    float vol[4];
    float sc[4];

    if (e0 + 4 <= E) {
        v4f rq[9];
        const v4f* Rp = (const v4f*)(rinv + 36 * (size_t)t);  // 144t bytes: 16B-aligned
        #pragma unroll
        for (int k = 0; k < 9; ++k)
            rq[k] = __builtin_nontemporal_load(Rp + k);
        const v4f vv = __builtin_nontemporal_load((const v4f*)(vols + 4 * (size_t)t));
        #pragma unroll
        for (int i = 0; i < 4; ++i)
            idx[i] = __builtin_nontemporal_load((const v4i*)elems + (4 * (size_t)t + i));
        #pragma unroll
        for (int k = 0; k < 9; ++k)
            #pragma unroll
            for (int j = 0; j < 4; ++j)
                rf[4 * k + j] = rq[k][j];   // flat rinv[36t + 4k + j]
        #pragma unroll
        for (int i = 0; i < 4; ++i) { vol[i] = vv[i]; sc[i] = sS; }
    } else {
        #pragma unroll
        for (int i = 0; i < 4; ++i) {
            const int e  = e0 + i;
            const int ec = e < E ? e : (E - 1);
            sc[i]  = e < E ? sS : 0.0f;
            vol[i] = __builtin_nontemporal_load(vols + ec);
            idx[i] = __builtin_nontemporal_load((const v4i*)elems + ec);
            #pragma unroll
            for (int k = 0; k < 9; ++k)
                rf[9 * i + k] = __builtin_nontemporal_load(rinv + 9 * (size_t)ec + k);
        }
    }

    if (PACKED) {
        uint2 gq[4][4];
        #pragma unroll
        for (int i = 0; i < 4; ++i)
            #pragma unroll
            for (int j = 0; j < 4; ++j)
                gq[i][j] = g_tab[(unsigned)idx[i][j]];  // cached: L2-resident table

        // Pin the whole load cluster live at one point (prevents round-0's
        // register-minimizing serialization; 36 VGPR -> full MLP).
        asm volatile("" ::
            "v"(gq[0][0].x), "v"(gq[0][0].y), "v"(gq[0][1].x), "v"(gq[0][1].y),
            "v"(gq[0][2].x), "v"(gq[0][2].y), "v"(gq[0][3].x), "v"(gq[0][3].y),
            "v"(gq[1][0].x), "v"(gq[1][0].y), "v"(gq[1][1].x), "v"(gq[1][1].y),
            "v"(gq[1][2].x), "v"(gq[1][2].y), "v"(gq[1][3].x), "v"(gq[1][3].y));
        asm volatile("" ::
            "v"(gq[2][0].x), "v"(gq[2][0].y), "v"(gq[2][1].x), "v"(gq[2][1].y),
            "v"(gq[2][2].x), "v"(gq[2][2].y), "v"(gq[2][3].x), "v"(gq[2][3].y),
            "v"(gq[3][0].x), "v"(gq[3][0].y), "v"(gq[3][1].x), "v"(gq[3][1].y),
            "v"(gq[3][2].x), "v"(gq[3][2].y), "v"(gq[3][3].x), "v"(gq[3][3].y));
        asm volatile("" ::
            "v"(rf[0]),  "v"(rf[1]),  "v"(rf[2]),  "v"(rf[3]),  "v"(rf[4]),
            "v"(rf[5]),  "v"(rf[6]),  "v"(rf[7]),  "v"(rf[8]),  "v"(rf[9]),
            "v"(rf[10]), "v"(rf[11]), "v"(rf[12]), "v"(rf[13]), "v"(rf[14]),
            "v"(rf[15]), "v"(rf[16]), "v"(rf[17]));
        asm volatile("" ::
            "v"(rf[18]), "v"(rf[19]), "v"(rf[20]), "v"(rf[21]), "v"(rf[22]),
            "v"(rf[23]), "v"(rf[24]), "v"(rf[25]), "v"(rf[26]), "v"(rf[27]),
            "v"(rf[28]), "v"(rf[29]), "v"(rf[30]), "v"(rf[31]), "v"(rf[32]),
            "v"(rf[33]), "v"(rf[34]), "v"(rf[35]),
            "v"(vol[0]), "v"(vol[1]), "v"(vol[2]), "v"(vol[3]));

        #pragma unroll
        for (int i = 0; i < 4; ++i) {
            float x[4][3];
            #pragma unroll
            for (int j = 0; j < 4; ++j)
                dec3(gq[i][j], x[j]);

            float d[3][3], F[3][3];
            #pragma unroll
            for (int r = 0; r < 3; ++r) {
                d[r][0] = x[1][r] - x[0][r];
                d[r][1] = x[2][r] - x[0][r];
                d[r][2] = x[3][r] - x[0][r];
            }
            #pragma unroll
            for (int r = 0; r < 3; ++r)
                #pragma unroll
                for (int k = 0; k < 3; ++k)
                    F[r][k] = d[r][0] * rf[9 * i + 0 + k]
                            + d[r][1] * rf[9 * i + 3 + k]
                            + d[r][2] * rf[9 * i + 6 + k];
            float det = F[0][0] * (F[1][1] * F[2][2] - F[1][2] * F[2][1])
                      - F[0][1] * (F[1][0] * F[2][2] - F[1][2] * F[2][0])
                      + F[0][2] * (F[1][0] * F[2][1] - F[1][1] * F[2][0]);

            if (fabsf(det) < 0.5f) {
                // Rare (~1%) fp32 redo: exact math where log-det is touchy.
                const float* p0 = pn + 3 * (size_t)idx[i].x;
                const float* p1 = pn + 3 * (size_t)idx[i].y;
                const float* p2 = pn + 3 * (size_t)idx[i].z;
                const float* p3 = pn + 3 * (size_t)idx[i].w;
                #pragma unroll
                for (int r = 0; r < 3; ++r) {
                    x[0][r] = p0[r]; x[1][r] = p1[r];
                    x[2][r] = p2[r]; x[3][r] = p3[r];
                }
                #pragma unroll
                for (int r = 0; r < 3; ++r) {
                    d[r][0] = x[1][r] - x[0][r];
                    d[r][1] = x[2][r] - x[0][r];
                    d[r][2] = x[3][r] - x[0][r];
                }
                #pragma unroll
                for (int r = 0; r < 3; ++r)
                    #pragma unroll
                    for (int k = 0; k < 3; ++k)
                        F[r][k] = d[r][0] * rf[9 * i + 0 + k]
                                + d[r][1] * rf[9 * i + 3 + k]
                                + d[r][2] * rf[9 * i + 6 + k];
                det = F[0][0] * (F[1][1] * F[2][2] - F[1][2] * F[2][1])
                    - F[0][1] * (F[1][0] * F[2][2] - F[1][2] * F[2][0])
                    + F[0][2] * (F[1][0] * F[2][1] - F[1][1] * F[2][0]);
            }

            const float ld = logf(fmaxf(det, 1e-8f));
            float tr = 0.0f;
            #pragma unroll
            for (int r = 0; r < 3; ++r)
                #pragma unroll
                for (int k = 0; k < 3; ++k)
                    tr += F[r][k] * F[r][k];
            const float psi = 0.5f * lam * ld * ld - mu * ld + 0.5f * mu * (tr - 3.0f);
            local += sc[i] * (psi * vol[i]);
        }
    } else {
        // Fallback (V > TAB_CAP_V): round-0-style serialized fp32 gathers.
        #pragma unroll
        for (int i = 0; i < 4; ++i) {
            float x[4][3];
            const float* p0 = pn + 3 * (size_t)idx[i].x;
            const float* p1 = pn + 3 * (size_t)idx[i].y;
            const float* p2 = pn + 3 * (size_t)idx[i].z;
            const float* p3 = pn + 3 * (size_t)idx[i].w;
            #pragma unroll
            for (int r = 0; r < 3; ++r) {
                x[0][r] = p0[r]; x[1][r] = p1[r];
                x[2][r] = p2[r]; x[3][r] = p3[r];
            }
            float d[3][3], F[3][3];
            #pragma unroll
            for (int r = 0; r < 3; ++r) {
                d[r][0] = x[1][r] - x[0][r];
                d[r][1] = x[2][r] - x[0][r];
                d[r][2] = x[3][r] - x[0][r];
            }
            #pragma unroll
            for (int r = 0; r < 3; ++r)
                #pragma unroll
                for (int k = 0; k < 3; ++k)
                    F[r][k] = d[r][0] * rf[9 * i + 0 + k]
                            + d[r][1] * rf[9 * i + 3 + k]
                            + d[r][2] * rf[9 * i + 6 + k];
            const float det = F[0][0] * (F[1][1] * F[2][2] - F[1][2] * F[2][1])
                            - F[0][1] * (F[1][0] * F[2][2] - F[1][2] * F[2][0])
                            + F[0][2] * (F[1][0] * F[2][1] - F[1][1] * F[2][0]);
            const float ld = logf(fmaxf(det, 1e-8f));
            float tr = 0.0f;
            #pragma unroll
            for (int r = 0; r < 3; ++r)
                #pragma unroll
                for (int k = 0; k < 3; ++k)
                    tr += F[r][k] * F[r][k];
            const float psi = 0.5f * lam * ld * ld - mu * ld + 0.5f * mu * (tr - 3.0f);
            local += sc[i] * (psi * vol[i]);
        }
    }

    const float tot = blockReduceSum(local);
    if (threadIdx.x == 0) partials[blockIdx.x] = tot;
}

__global__ void reduce_kernel(const float* __restrict__ partials, int n,
                              float* __restrict__ out) {
    double s = 0.0;
    for (int i = threadIdx.x; i < n; i += blockDim.x)
        s += (double)partials[i];
    __shared__ double sm[256];
    sm[threadIdx.x] = s;
    __syncthreads();
    #pragma unroll
    for (int off = 128; off > 0; off >>= 1) {
        if (threadIdx.x < off) sm[threadIdx.x] += sm[threadIdx.x + off];
        __syncthreads();
    }
    if (threadIdx.x == 0) out[0] = (float)sm[0];
}

extern "C" void kernel_launch(void* const* d_in, const int* in_sizes, int n_in,
                              void* d_out, int out_size, void* d_ws, size_t ws_size,
                              hipStream_t stream) {
    const float* pos_next = (const float*)d_in[0];
    const float* pos_curr = (const float*)d_in[1];
    const float* pos_prev = (const float*)d_in[2];
    const float* mass     = (const float*)d_in[3];
    const int*   elements = (const int*)d_in[4];
    const float* rest_vol = (const float*)d_in[5];
    const float* rest_inv = (const float*)d_in[6];
    const float* lam_p    = (const float*)d_in[7];
    const float* mu_p     = (const float*)d_in[8];
    float* out = (float*)d_out;

    const int V = in_sizes[3];  // mass has V elements
    const int E = in_sizes[5];  // rest_volumes has E elements

    const float sI = 0.5f / (3.0f * (float)V);       // W_INERTIA * 0.5 / (3V)
    const float sG = -0.01f * GRAVITY_F / (float)V;  // W_GRAVITY * (-g) / V
    const float sS = 1.0f / (float)E;                // W_STRAIN / E

    const int block = 256;
    const int gridV = (((V + 3) / 4) + block - 1) / block;
    const int gridE = (((E + 3) / 4) + block - 1) / block;
    const int grid  = gridV + gridE;
    const int doPack = (V <= TAB_CAP_V) ? 1 : 0;

    float* partials = (float*)d_ws;  // grid floats (~10 KB): every slot overwritten

    pack_vert_kernel<<<gridV, block, 0, stream>>>(pos_next, pos_curr, pos_prev,
                                                  mass, partials, V, doPack, sI, sG);
    if (doPack) {
        elem_kernel<true><<<gridE, block, 0, stream>>>(pos_next, elements, rest_vol,
                                                       rest_inv, lam_p, mu_p,
                                                       partials + gridV, E, sS);
    } else {
        elem_kernel<false><<<gridE, block, 0, stream>>>(pos_next, elements, rest_vol,
                                                        rest_inv, lam_p, mu_p,
                                                        partials + gridV, E, sS);
    }
    reduce_kernel<<<1, 256, 0, stream>>>(partials, grid, out);
}